// Round 3
// baseline (3416.615 us; speedup 1.0000x reference)
//
#include <hip/hip_runtime.h>
#include <hip/hip_fp16.h>
#include <cstdint>
#include <cstddef>

#define B_ 4
#define S_ 4096
#define D_ 1024
#define E_ 1536
#define M_ (B_*S_)   // 16384 rows

#define TS 64
#define KS 16

__device__ __forceinline__ unsigned int packcv(float c, float v) {
  return (unsigned int)__half_as_ushort(__float2half_rn(c)) |
         ((unsigned int)__half_as_ushort(__float2half_rn(v)) << 16);
}
__device__ __forceinline__ float h2f(unsigned short u) {
  return __half2float(__ushort_as_half(u));
}

// ---------- GEMM1 fused with pointwise gate math ----------
// hidden[m,e] = sum_d X[m,d]*W[e,d];  gate[m,e] = sum_d X[m,d]*W[e+E_,d]
// c = sigmoid(-gate); v = sigmoid(gate)*g(hidden); packed fp16 pair (lo=c, hi=v).
__global__ __launch_bounds__(256) void gemm1_pw(const float* __restrict__ X,
                                                const float* __restrict__ W,
                                                unsigned int* __restrict__ CV) {
  __shared__ float As[TS][KS + 1];
  __shared__ float Bh[TS][KS + 1];
  __shared__ float Bg[TS][KS + 1];
  const int tid = threadIdx.x;
  const int m0 = blockIdx.x * TS;
  const int n0 = blockIdx.y * TS;
  const int lr = tid >> 2;          // 0..63
  const int lc = (tid & 3) << 2;    // 0,4,8,12
  const int ty = tid >> 4;          // 0..15
  const int tx = tid & 15;          // 0..15
  float ah[4][4] = {{0.f}};
  float ag[4][4] = {{0.f}};
  for (int k0 = 0; k0 < D_; k0 += KS) {
    float4 a4 = *(const float4*)(X + (size_t)(m0 + lr) * D_ + k0 + lc);
    float4 h4 = *(const float4*)(W + (size_t)(n0 + lr) * D_ + k0 + lc);
    float4 g4 = *(const float4*)(W + (size_t)(n0 + lr + E_) * D_ + k0 + lc);
    As[lr][lc + 0] = a4.x; As[lr][lc + 1] = a4.y; As[lr][lc + 2] = a4.z; As[lr][lc + 3] = a4.w;
    Bh[lr][lc + 0] = h4.x; Bh[lr][lc + 1] = h4.y; Bh[lr][lc + 2] = h4.z; Bh[lr][lc + 3] = h4.w;
    Bg[lr][lc + 0] = g4.x; Bg[lr][lc + 1] = g4.y; Bg[lr][lc + 2] = g4.z; Bg[lr][lc + 3] = g4.w;
    __syncthreads();
#pragma unroll
    for (int k = 0; k < KS; ++k) {
      float a[4], bh[4], bg[4];
#pragma unroll
      for (int i = 0; i < 4; ++i) a[i] = As[ty * 4 + i][k];
#pragma unroll
      for (int j = 0; j < 4; ++j) { bh[j] = Bh[tx * 4 + j][k]; bg[j] = Bg[tx * 4 + j][k]; }
#pragma unroll
      for (int i = 0; i < 4; ++i)
#pragma unroll
        for (int j = 0; j < 4; ++j) {
          ah[i][j] = fmaf(a[i], bh[j], ah[i][j]);
          ag[i][j] = fmaf(a[i], bg[j], ag[i][j]);
        }
    }
    __syncthreads();
  }
#pragma unroll
  for (int i = 0; i < 4; ++i) {
#pragma unroll
    for (int j = 0; j < 4; ++j) {
      const int m = m0 + ty * 4 + i;
      const int e = n0 + tx * 4 + j;
      const float hid = ah[i][j];
      const float gat = ag[i][j];
      const float z = 1.f / (1.f + expf(-gat));      // sigmoid(gate)
      const float c = 1.f / (1.f + expf(gat));       // sigmoid(-gate) = 1-z
      const float gv = (hid >= 0.f) ? (hid + 0.5f) : (1.f / (1.f + expf(-hid)));
      CV[(size_t)m * E_ + e] = packcv(c, z * gv);
    }
  }
}

// ---------- bidirectional scan ----------
// h_fwd at out index j: recurrence t=0..j ; h_bwd at out index j: recurrence
// t=S-1..S-1-j (time-flipped input, NOT flipped back). Both land at index j.
__global__ __launch_bounds__(256) void scan_bi(const unsigned int* __restrict__ CV,
                                               unsigned short* __restrict__ H) {
  const int idx = blockIdx.x * blockDim.x + threadIdx.x;  // 0..B_*E_-1
  const int b = idx / E_;
  const int e = idx - b * E_;
  const unsigned int* cvp = CV + (size_t)b * S_ * E_ + e;
  unsigned short* hp = H + (size_t)b * S_ * E_ + e;
  float hf = 0.f, hb = 0.f;
#pragma unroll 4
  for (int j = 0; j < S_; ++j) {
    const unsigned int pf = cvp[(size_t)j * E_];
    const unsigned int pb = cvp[(size_t)(S_ - 1 - j) * E_];
    hf = fmaf(h2f((unsigned short)pf), hf, h2f((unsigned short)(pf >> 16)));
    hb = fmaf(h2f((unsigned short)pb), hb, h2f((unsigned short)(pb >> 16)));
    hp[(size_t)j * E_] = __half_as_ushort(__float2half_rn(hf + hb));
  }
}

// ---------- GEMM2 ----------
// out[m,d] = sum_e H[m,e] * Wo[d,e]   (Wo row-major [D_, E_], contiguous in e)
__global__ __launch_bounds__(256) void gemm2_k(const unsigned short* __restrict__ H,
                                               const float* __restrict__ Wo,
                                               float* __restrict__ Out) {
  __shared__ float As[TS][KS + 1];
  __shared__ float Bs[TS][KS + 1];
  const int tid = threadIdx.x;
  const int m0 = blockIdx.x * TS;
  const int n0 = blockIdx.y * TS;
  const int lr = tid >> 2;
  const int lc = (tid & 3) << 2;
  const int ty = tid >> 4;
  const int tx = tid & 15;
  float acc[4][4] = {{0.f}};
  for (int k0 = 0; k0 < E_; k0 += KS) {
    ushort4 a4 = *(const ushort4*)(H + (size_t)(m0 + lr) * E_ + k0 + lc);
    float4 b4 = *(const float4*)(Wo + (size_t)(n0 + lr) * E_ + k0 + lc);
    As[lr][lc + 0] = h2f(a4.x); As[lr][lc + 1] = h2f(a4.y); As[lr][lc + 2] = h2f(a4.z); As[lr][lc + 3] = h2f(a4.w);
    Bs[lr][lc + 0] = b4.x; Bs[lr][lc + 1] = b4.y; Bs[lr][lc + 2] = b4.z; Bs[lr][lc + 3] = b4.w;
    __syncthreads();
#pragma unroll
    for (int k = 0; k < KS; ++k) {
      float a[4], b[4];
#pragma unroll
      for (int i = 0; i < 4; ++i) a[i] = As[ty * 4 + i][k];
#pragma unroll
      for (int j = 0; j < 4; ++j) b[j] = Bs[tx * 4 + j][k];
#pragma unroll
      for (int i = 0; i < 4; ++i)
#pragma unroll
        for (int j = 0; j < 4; ++j) acc[i][j] = fmaf(a[i], b[j], acc[i][j]);
    }
    __syncthreads();
  }
#pragma unroll
  for (int i = 0; i < 4; ++i)
#pragma unroll
    for (int j = 0; j < 4; ++j) {
      const int m = m0 + ty * 4 + i;
      const int d = n0 + tx * 4 + j;
      Out[(size_t)m * D_ + d] = acc[i][j];
    }
}

extern "C" void kernel_launch(void* const* d_in, const int* in_sizes, int n_in,
                              void* d_out, int out_size, void* d_ws, size_t ws_size,
                              hipStream_t stream) {
  const float* x    = (const float*)d_in[0];   // [4,4096,1024] fp32
  const float* whg  = (const float*)d_in[1];   // [3072,1024]  fp32
  const float* wout = (const float*)d_in[2];   // [1024,1536]  fp32
  float* out = (float*)d_out;                  // [4,4096,1024] fp32

  unsigned int*  CV = (unsigned int*)d_ws;                       // [16384,1536] fp16 pair (c,v) = 100.7 MB
  unsigned short* Hs = (unsigned short*)(CV + (size_t)M_ * E_);  // [16384,1536] fp16 = 50.3 MB -> 151 MB total

  gemm1_pw<<<dim3(M_ / TS, E_ / TS), 256, 0, stream>>>(x, whg, CV);
  scan_bi<<<dim3((B_ * E_) / 256), 256, 0, stream>>>(CV, Hs);
  gemm2_k<<<dim3(M_ / TS, D_ / TS), 256, 0, stream>>>(Hs, wout, out);
}

// Round 4
// 416.929 us; speedup vs baseline: 8.1947x; 8.1947x over previous
//
#include <hip/hip_runtime.h>
#include <hip/hip_fp16.h>
#include <cstdint>
#include <cstddef>

#define B_ 4
#define S_ 4096
#define D_ 1024
#define E_ 1536
#define M_ (B_*S_)       // 16384
#define BE_ (B_*E_)      // 6144
#define C_ 32            // scan chunks
#define L_ (S_/C_)       // 128

typedef short bf16x8 __attribute__((ext_vector_type(8)));
typedef float f32x4 __attribute__((ext_vector_type(4)));

__device__ __forceinline__ unsigned short f2b(float f) {
  union { float f; unsigned int i; } x; x.f = f;
  unsigned int r = x.i + 0x7FFFu + ((x.i >> 16) & 1u);   // RNE
  return (unsigned short)(r >> 16);
}
__device__ __forceinline__ float h2f(unsigned short u) { return __half2float(__ushort_as_half(u)); }
__device__ __forceinline__ unsigned int packcv(float c, float v) {
  return (unsigned int)__half_as_ushort(__float2half_rn(c)) |
         ((unsigned int)__half_as_ushort(__float2half_rn(v)) << 16);
}

// ---------- fp32 -> bf16 conversion (exact-cover grid) ----------
__global__ __launch_bounds__(256) void cvt_bf16(const float* __restrict__ src,
                                                unsigned short* __restrict__ dst) {
  const int i = blockIdx.x * 256 + threadIdx.x;
  float4 f = ((const float4*)src)[i];
  ushort4 u; u.x = f2b(f.x); u.y = f2b(f.y); u.z = f2b(f.z); u.w = f2b(f.w);
  ((ushort4*)dst)[i] = u;
}

// ---------- GEMM1 (MFMA bf16) fused with gate pointwise ----------
// h[m,e] = sum_d X[m,d]*W[e,d]; g[m,e] = sum_d X[m,d]*W[e+E_,d]
// block tile: 128 m x 64 e (=> 128 W rows incl. gate half). 4 waves, each 64m x 32e x {h,g}.
__global__ __launch_bounds__(256) void gemm1_mfma(const unsigned short* __restrict__ Xb,
                                                  const unsigned short* __restrict__ Wb,
                                                  unsigned int* __restrict__ CV) {
  __shared__ unsigned short lA[128 * 32];
  __shared__ unsigned short lB[128 * 32];
  const int t = threadIdx.x;
  const int m0 = blockIdx.x * 128;
  const int n0 = blockIdx.y * 64;
  const int wv = t >> 6, lane = t & 63;
  const int wm = wv >> 1, we = wv & 1;         // 2x2 wave grid
  const int lm = lane & 15, kg = lane >> 4;
  // staging: thread t covers 16B chunks (t) and (t+256) of each 8KB tile
  const int r1 = t >> 2, q1 = t & 3;           // rows 0..63
  const int r2 = r1 + 64;                      // rows 64..127
  const int gb1 = (r1 < 64) ? (n0 + r1) : (E_ + n0 + r1 - 64);
  const int gb2 = (r2 < 64) ? (n0 + r2) : (E_ + n0 + r2 - 64);

  const f32x4 z4 = {0.f, 0.f, 0.f, 0.f};
  f32x4 ah[4][2], ag[4][2];
#pragma unroll
  for (int i = 0; i < 4; ++i)
#pragma unroll
    for (int j = 0; j < 2; ++j) { ah[i][j] = z4; ag[i][j] = z4; }

  for (int k0 = 0; k0 < D_; k0 += 32) {
    *(uint4*)(lA + (size_t)r1 * 32 + q1 * 8) = *(const uint4*)(Xb + (size_t)(m0 + r1) * D_ + k0 + q1 * 8);
    *(uint4*)(lA + (size_t)r2 * 32 + q1 * 8) = *(const uint4*)(Xb + (size_t)(m0 + r2) * D_ + k0 + q1 * 8);
    *(uint4*)(lB + (size_t)r1 * 32 + q1 * 8) = *(const uint4*)(Wb + (size_t)gb1 * D_ + k0 + q1 * 8);
    *(uint4*)(lB + (size_t)r2 * 32 + q1 * 8) = *(const uint4*)(Wb + (size_t)gb2 * D_ + k0 + q1 * 8);
    __syncthreads();
    bf16x8 af[4], bh[2], bg[2];
#pragma unroll
    for (int mt = 0; mt < 4; ++mt)
      af[mt] = *(const bf16x8*)(lA + (size_t)(wm * 64 + mt * 16 + lm) * 32 + kg * 8);
#pragma unroll
    for (int et = 0; et < 2; ++et) {
      bh[et] = *(const bf16x8*)(lB + (size_t)(we * 32 + et * 16 + lm) * 32 + kg * 8);
      bg[et] = *(const bf16x8*)(lB + (size_t)(64 + we * 32 + et * 16 + lm) * 32 + kg * 8);
    }
#pragma unroll
    for (int mt = 0; mt < 4; ++mt)
#pragma unroll
      for (int et = 0; et < 2; ++et) {
        ah[mt][et] = __builtin_amdgcn_mfma_f32_16x16x32_bf16(af[mt], bh[et], ah[mt][et], 0, 0, 0);
        ag[mt][et] = __builtin_amdgcn_mfma_f32_16x16x32_bf16(af[mt], bg[et], ag[mt][et], 0, 0, 0);
      }
    __syncthreads();
  }
  // epilogue: C/D layout col=lane&15, row=kg*4+reg
#pragma unroll
  for (int mt = 0; mt < 4; ++mt)
#pragma unroll
    for (int et = 0; et < 2; ++et) {
      const int e = n0 + we * 32 + et * 16 + lm;
#pragma unroll
      for (int r = 0; r < 4; ++r) {
        const int m = m0 + wm * 64 + mt * 16 + kg * 4 + r;
        const float hid = ah[mt][et][r];
        const float gat = ag[mt][et][r];
        const float z = 1.f / (1.f + expf(-gat));
        const float c = 1.f / (1.f + expf(gat));
        const float gv = (hid >= 0.f) ? (hid + 0.5f) : (1.f / (1.f + expf(-hid)));
        CV[(size_t)m * E_ + e] = packcv(c, z * gv);
      }
    }
}

// ---------- scan pass 1: per-chunk (P, Qf, Qr) ----------
__global__ __launch_bounds__(256) void scan_p1(const unsigned int* __restrict__ CV,
                                               float* __restrict__ P, float* __restrict__ Qf,
                                               float* __restrict__ Qr) {
  const int be = blockIdx.x * 256 + threadIdx.x;
  const int b = be / E_, e = be - b * E_;
  const int k = blockIdx.y;
  const unsigned int* cv = CV + (size_t)b * S_ * E_ + e + (size_t)k * L_ * E_;
  float pp = 1.f, qf = 0.f, qr = 0.f;
  for (int l = 0; l < L_; ++l) {
    const unsigned int p = cv[(size_t)l * E_];
    const float c = h2f((unsigned short)p), v = h2f((unsigned short)(p >> 16));
    qf = fmaf(c, qf, v);       // scan from zero, ascending
    qr = fmaf(pp, v, qr);      // scan from zero, descending (prefix-product form)
    pp *= c;
  }
  P[(size_t)k * BE_ + be] = pp;
  Qf[(size_t)k * BE_ + be] = qf;
  Qr[(size_t)k * BE_ + be] = qr;
}

// ---------- scan pass 2: chunk-level prefix (tiny) ----------
__global__ __launch_bounds__(256) void scan_p2(const float* __restrict__ P, const float* __restrict__ Qf,
                                               const float* __restrict__ Qr, float* __restrict__ HfIn,
                                               float* __restrict__ HbIn) {
  const int be = blockIdx.x * 256 + threadIdx.x;
  float hf = 0.f;
  for (int k = 0; k < C_; ++k) {
    HfIn[(size_t)k * BE_ + be] = hf;
    hf = fmaf(P[(size_t)k * BE_ + be], hf, Qf[(size_t)k * BE_ + be]);
  }
  float hb = 0.f;
  for (int k = C_ - 1; k >= 0; --k) {
    HbIn[(size_t)k * BE_ + be] = hb;   // state after consuming original chunks > k
    hb = fmaf(P[(size_t)k * BE_ + be], hb, Qr[(size_t)k * BE_ + be]);
  }
}

// ---------- scan pass 3: replay with carry-ins, write H = hf + hb (bf16) ----------
__global__ __launch_bounds__(256) void scan_p3(const unsigned int* __restrict__ CV,
                                               const float* __restrict__ HfIn,
                                               const float* __restrict__ HbIn,
                                               unsigned short* __restrict__ Hb) {
  const int be = blockIdx.x * 256 + threadIdx.x;
  const int b = be / E_, e = be - b * E_;
  const int k = blockIdx.y;                    // output chunk
  const unsigned int* cv = CV + (size_t)b * S_ * E_ + e;
  const unsigned int* cvf = cv + (size_t)k * L_ * E_;                 // ascending
  const unsigned int* cvb = cv + (size_t)(S_ - 1 - k * L_) * E_;      // descending
  unsigned short* hp = Hb + (size_t)b * S_ * E_ + e + (size_t)k * L_ * E_;
  float hf = HfIn[(size_t)k * BE_ + be];
  float hb = HbIn[(size_t)(C_ - 1 - k) * BE_ + be];
  for (int l = 0; l < L_; ++l) {
    const unsigned int pf = cvf[(size_t)l * E_];
    const unsigned int pb = *(cvb - (ptrdiff_t)l * E_);
    hf = fmaf(h2f((unsigned short)pf), hf, h2f((unsigned short)(pf >> 16)));
    hb = fmaf(h2f((unsigned short)pb), hb, h2f((unsigned short)(pb >> 16)));
    hp[(size_t)l * E_] = f2b(hf + hb);
  }
}

// ---------- GEMM2 (MFMA bf16): out[m,d] = sum_e H[m,e]*Wo[d,e] ----------
// block tile 128 m x 128 d, 4 waves each 64x64.
__global__ __launch_bounds__(256) void gemm2_mfma(const unsigned short* __restrict__ Hb,
                                                  const unsigned short* __restrict__ Wob,
                                                  float* __restrict__ Out) {
  __shared__ unsigned short lA[128 * 32];
  __shared__ unsigned short lB[128 * 32];
  const int t = threadIdx.x;
  const int m0 = blockIdx.x * 128;
  const int n0 = blockIdx.y * 128;
  const int wv = t >> 6, lane = t & 63;
  const int wm = wv >> 1, wn = wv & 1;
  const int lm = lane & 15, kg = lane >> 4;
  const int r1 = t >> 2, q1 = t & 3;
  const int r2 = r1 + 64;

  const f32x4 z4 = {0.f, 0.f, 0.f, 0.f};
  f32x4 acc[4][4];
#pragma unroll
  for (int i = 0; i < 4; ++i)
#pragma unroll
    for (int j = 0; j < 4; ++j) acc[i][j] = z4;

  for (int k0 = 0; k0 < E_; k0 += 32) {
    *(uint4*)(lA + (size_t)r1 * 32 + q1 * 8) = *(const uint4*)(Hb + (size_t)(m0 + r1) * E_ + k0 + q1 * 8);
    *(uint4*)(lA + (size_t)r2 * 32 + q1 * 8) = *(const uint4*)(Hb + (size_t)(m0 + r2) * E_ + k0 + q1 * 8);
    *(uint4*)(lB + (size_t)r1 * 32 + q1 * 8) = *(const uint4*)(Wob + (size_t)(n0 + r1) * E_ + k0 + q1 * 8);
    *(uint4*)(lB + (size_t)r2 * 32 + q1 * 8) = *(const uint4*)(Wob + (size_t)(n0 + r2) * E_ + k0 + q1 * 8);
    __syncthreads();
    bf16x8 af[4], bf[4];
#pragma unroll
    for (int mt = 0; mt < 4; ++mt)
      af[mt] = *(const bf16x8*)(lA + (size_t)(wm * 64 + mt * 16 + lm) * 32 + kg * 8);
#pragma unroll
    for (int nt = 0; nt < 4; ++nt)
      bf[nt] = *(const bf16x8*)(lB + (size_t)(wn * 64 + nt * 16 + lm) * 32 + kg * 8);
#pragma unroll
    for (int mt = 0; mt < 4; ++mt)
#pragma unroll
      for (int nt = 0; nt < 4; ++nt)
        acc[mt][nt] = __builtin_amdgcn_mfma_f32_16x16x32_bf16(af[mt], bf[nt], acc[mt][nt], 0, 0, 0);
    __syncthreads();
  }
#pragma unroll
  for (int mt = 0; mt < 4; ++mt)
#pragma unroll
    for (int nt = 0; nt < 4; ++nt) {
      const int d = n0 + wn * 64 + nt * 16 + lm;
#pragma unroll
      for (int r = 0; r < 4; ++r) {
        const int m = m0 + wm * 64 + mt * 16 + kg * 4 + r;
        Out[(size_t)m * D_ + d] = acc[mt][nt][r];
      }
    }
}

extern "C" void kernel_launch(void* const* d_in, const int* in_sizes, int n_in,
                              void* d_out, int out_size, void* d_ws, size_t ws_size,
                              hipStream_t stream) {
  const float* x    = (const float*)d_in[0];   // [4,4096,1024] fp32
  const float* whg  = (const float*)d_in[1];   // [3072,1024]  fp32
  const float* wout = (const float*)d_in[2];   // [1024,1536]  fp32
  float* out = (float*)d_out;                  // [4,4096,1024] fp32

  // ws (151 MB, proven-safe): [CV: M*E*4 = 100.7MB][H: M*E*2 = 50.3MB]
  unsigned int*  CV = (unsigned int*)d_ws;
  unsigned short* Hb = (unsigned short*)((char*)d_ws + (size_t)M_ * E_ * 4);
  // phase-overlapped aliases:
  unsigned short* Xb  = Hb;                     // bf16 X lives in H region until scan writes H
  unsigned short* Wb  = Xb + (size_t)M_ * D_;   // bf16 W_hg after it (39.9MB <= 50.3MB)
  unsigned short* Wob = (unsigned short*)d_ws;  // bf16 W_out in CV region (CV dead after scan)
  // scan chunk scratch lives in d_out (gemm2 fully overwrites it afterwards)
  float* P    = out;
  float* Qf   = out + (size_t)C_ * BE_;
  float* Qr   = out + 2 * (size_t)C_ * BE_;
  float* HfIn = out + 3 * (size_t)C_ * BE_;
  float* HbIn = out + 4 * (size_t)C_ * BE_;

  cvt_bf16<<<M_ * D_ / 1024, 256, 0, stream>>>(x, Xb);
  cvt_bf16<<<2 * E_ * D_ / 1024, 256, 0, stream>>>(whg, Wb);
  gemm1_mfma<<<dim3(M_ / 128, E_ / 64), 256, 0, stream>>>(Xb, Wb, CV);
  scan_p1<<<dim3(BE_ / 256, C_), 256, 0, stream>>>(CV, P, Qf, Qr);
  scan_p2<<<BE_ / 256, 256, 0, stream>>>(P, Qf, Qr, HfIn, HbIn);
  scan_p3<<<dim3(BE_ / 256, C_), 256, 0, stream>>>(CV, HfIn, HbIn, Hb);
  cvt_bf16<<<D_ * E_ / 1024, 256, 0, stream>>>(wout, Wob);
  gemm2_mfma<<<dim3(M_ / 128, D_ / 128), 256, 0, stream>>>(Hb, Wob, out);
}